// Round 6
// baseline (506.906 us; speedup 1.0000x reference)
//
#include <hip/hip_runtime.h>
#include <hip/hip_bf16.h>

#define B_ 4
#define S_ 512
#define E_ 512
#define U_ 256
#define NBLK 1024

// 2*log2(e): folded so tanh args feed exp2 directly: exp(2x) = exp2(KC*x)
#define KC 2.885390081777927f

#if __has_builtin(__builtin_amdgcn_exp2f)
#define EXP2F(x) __builtin_amdgcn_exp2f(x)
#else
#define EXP2F(x) __exp2f(x)
#endif
#if __has_builtin(__builtin_amdgcn_rcpf)
#define RCPF(x) __builtin_amdgcn_rcpf(x)
#else
#define RCPF(x) (1.0f / (x))
#endif

typedef __attribute__((ext_vector_type(8))) short bf16x8;
typedef __attribute__((ext_vector_type(4))) float f32x4;

__device__ __forceinline__ unsigned short bf16rn(float x) {
    unsigned int u = __float_as_uint(x);
    u = (u + 0x7FFFu + ((u >> 16) & 1u)) >> 16;   // RNE
    return (unsigned short)u;
}

// truncation split: x = hi + lo + O(2^-17 x); lo = x - hi is exact in fp32
__device__ __forceinline__ void splitT(float x, short* hi, short* lo) {
    const unsigned u = __float_as_uint(x);
    *hi = (short)(u >> 16);
    const float hf = __uint_as_float(u & 0xFFFF0000u);
    *lo = (short)(__float_as_uint(x - hf) >> 16);
}

// device-scope grid barrier; slot must be 0 before the kernel starts.
__device__ __forceinline__ void grid_bar(int* slot) {
    __syncthreads();
    if (threadIdx.x == 0) {
        __hip_atomic_fetch_add(slot, 1, __ATOMIC_ACQ_REL, __HIP_MEMORY_SCOPE_AGENT);
        while (__hip_atomic_load(slot, __ATOMIC_ACQUIRE, __HIP_MEMORY_SCOPE_AGENT) < NBLK)
            __builtin_amdgcn_s_sleep(2);
    }
    __syncthreads();
}

// 4-way batched tanh-dot term: acc += sum_{q=0..3} v_q / F_q, F = exp2(arg)+1
__device__ __forceinline__ float quadTerm(float a0, float a1, float a2, float a3,
                                          float4 vq, float acc) {
    const float F1 = EXP2F(a0) + 1.f;
    const float F2 = EXP2F(a1) + 1.f;
    const float F3 = EXP2F(a2) + 1.f;
    const float F4 = EXP2F(a3) + 1.f;
    const float P12 = F1 * F2, P34 = F3 * F4;
    const float n12 = fmaf(vq.y, F1, vq.x * F2);
    const float n34 = fmaf(vq.w, F3, vq.z * F4);
    const float num = fmaf(n34, P12, n12 * P34);
    return fmaf(num, RCPF(P12 * P34), acc);
}

// ===========================================================================
// One kernel, three phases, two grid barriers. Grid MUST be exactly NBLK
// blocks of 256 thr; __launch_bounds__(256,4) caps VGPR<=128 so 4 blocks/CU
// (= NBLK/256CU) are co-resident -> software barrier cannot deadlock.
// ===========================================================================
__global__ void __launch_bounds__(256, 4)
fused_attend(const float* __restrict__ h1, const float* __restrict__ h2,
             const float* __restrict__ w, const float* __restrict__ b1,
             const float* __restrict__ v, float* __restrict__ out,
             float* __restrict__ keySt, float* __restrict__ qryS,
             unsigned short* __restrict__ Pp, int* __restrict__ bars)
{
    const int tid = threadIdx.x;
    const int bid = blockIdx.x;
    const int wv = tid >> 6, lane = tid & 63;
    const int quad = lane >> 4, l16 = lane & 15;

    __shared__ float ssm[4][2];

    // ---------------- Phase A: pre-GEMMs (MFMA hi/lo, 16x16 tile/wave) ----
    // 4096 wave-tasks: z (which projection) x 128 m-tiles x 16 n-tiles.
    //   z==0: keySt[b][u][j] = KC*(h1[b,j,:] @ w1[:,u])   (j contiguous)
    //   z==1: qryS [b][i][u] = KC*(h2[b,i,:] @ w2[:,u] + b1[u])
    {
        const int wt = bid * 4 + wv;
        const int z = wt >> 11, rem = wt & 2047;
        const int m0 = (rem >> 4) << 4, n0 = (rem & 15) << 4;
        const float* __restrict__ A = z ? h2 : h1;
        const float* __restrict__ Arow = A + (size_t)(m0 + l16) * E_;
        const float* __restrict__ Wcol = w + (size_t)z * E_ * U_ + n0 + l16;

        f32x4 acc = {0.f, 0.f, 0.f, 0.f};
        for (int kc = 0; kc < 16; ++kc) {
            const int kb = kc * 32 + quad * 8;
            const float4 x0 = *(const float4*)&Arow[kb];
            const float4 x1 = *(const float4*)&Arow[kb + 4];
            const float xs[8] = {x0.x, x0.y, x0.z, x0.w, x1.x, x1.y, x1.z, x1.w};
            bf16x8 ah, al;
#pragma unroll
            for (int j = 0; j < 8; ++j) {
                short h, l; splitT(xs[j], &h, &l);
                ah[j] = h; al[j] = l;
            }
            float ws8[8];
#pragma unroll
            for (int j = 0; j < 8; ++j)
                ws8[j] = Wcol[(size_t)(kb + j) * U_] * KC;
            bf16x8 wh, wl;
#pragma unroll
            for (int j = 0; j < 8; ++j) {
                short h, l; splitT(ws8[j], &h, &l);
                wh[j] = h; wl[j] = l;
            }
            acc = __builtin_amdgcn_mfma_f32_16x16x32_bf16(ah, wh, acc, 0, 0, 0);
            acc = __builtin_amdgcn_mfma_f32_16x16x32_bf16(ah, wl, acc, 0, 0, 0);
            acc = __builtin_amdgcn_mfma_f32_16x16x32_bf16(al, wh, acc, 0, 0, 0);
        }
        if (z == 0) {
            const int b = m0 >> 9;
            const int j0 = (m0 & (S_ - 1)) + quad * 4;     // C/D row = j
            const int u = n0 + l16;                        // C/D col = u
            *(float4*)&keySt[((size_t)b * U_ + u) * S_ + j0] =
                make_float4(acc[0], acc[1], acc[2], acc[3]);
        } else {
            const int row = m0 + quad * 4;
            const int u = n0 + l16;
            const float bias = KC * b1[u];
#pragma unroll
            for (int r = 0; r < 4; ++r)
                qryS[(size_t)(row + r) * U_ + u] = acc[r] + bias;
        }
    }

    grid_bar(&bars[0]);

    // ---------------- Phase B: scores + softmax -> packed bf16 P ----------
    // block <-> (b, 2 rows i); thread t <-> cols j = 2t, 2t+1.
    // a = sum_u v_u/(exp2(arg)+1); score = c - 2a (c, b2 cancel) ->
    // p = exp2(-a*KC), normalized. 1 rcp per 4 u via product batching.
    {
        const int b = bid >> 8;
        const int i0 = (bid & 255) << 1;
        const float* __restrict__ q0p = qryS + ((size_t)b * S_ + i0) * U_;
        const float4* __restrict__ q0v = (const float4*)q0p;
        const float4* __restrict__ q1v = (const float4*)(q0p + U_);
        const float4* __restrict__ vv4 = (const float4*)v;
        const float2* __restrict__ kb2 =
            (const float2*)(keySt + (size_t)b * U_ * S_) + tid;

        float a00 = 0.f, a01 = 0.f, a10 = 0.f, a11 = 0.f;
#pragma unroll 2
        for (int ub = 0; ub < U_ / 4; ++ub) {
            const float4 q0 = q0v[ub], q1 = q1v[ub], vq = vv4[ub];
            const float2 k0 = kb2[(ub * 4 + 0) * (S_ / 2)];
            const float2 k1 = kb2[(ub * 4 + 1) * (S_ / 2)];
            const float2 k2 = kb2[(ub * 4 + 2) * (S_ / 2)];
            const float2 k3 = kb2[(ub * 4 + 3) * (S_ / 2)];
            a00 = quadTerm(q0.x + k0.x, q0.y + k1.x, q0.z + k2.x, q0.w + k3.x, vq, a00);
            a01 = quadTerm(q0.x + k0.y, q0.y + k1.y, q0.z + k2.y, q0.w + k3.y, vq, a01);
            a10 = quadTerm(q1.x + k0.x, q1.y + k1.x, q1.z + k2.x, q1.w + k3.x, vq, a10);
            a11 = quadTerm(q1.x + k0.y, q1.y + k1.y, q1.z + k2.y, q1.w + k3.y, vq, a11);
        }

        // no max-shift needed: |a|*KC <= ~52, exp2 safe in fp32
        const float p00 = EXP2F(-a00 * KC), p01 = EXP2F(-a01 * KC);
        const float p10 = EXP2F(-a10 * KC), p11 = EXP2F(-a11 * KC);
        float s0 = p00 + p01, s1 = p10 + p11;
#pragma unroll
        for (int off = 1; off < 64; off <<= 1) {
            s0 += __shfl_xor(s0, off, 64);
            s1 += __shfl_xor(s1, off, 64);
        }
        if ((tid & 63) == 0) { ssm[wv][0] = s0; ssm[wv][1] = s1; }
        __syncthreads();
        s0 = (ssm[0][0] + ssm[1][0]) + (ssm[2][0] + ssm[3][0]);
        s1 = (ssm[0][1] + ssm[1][1]) + (ssm[2][1] + ssm[3][1]);
        const float r0 = RCPF(s0), r1 = RCPF(s1);

        // pack P into MFMA A-frag order (verified in R5):
        // slot = (itile*16 + (j>>5))*64 + ((i&15) | (((j>>3)&3)<<4)), elem j&7
        const int j2 = tid * 2;
        const int itile = i0 >> 4;
        const int base = (itile * 16 + (j2 >> 5)) * 64 + (((j2 >> 3) & 3) << 4);
        const int eo = tid & 3;                 // uint index inside slot
        unsigned* __restrict__ Pu = (unsigned*)(Pp + (size_t)b * S_ * S_);
        const unsigned w0 = (unsigned)bf16rn(p00 * r0) | ((unsigned)bf16rn(p01 * r0) << 16);
        const unsigned w1 = (unsigned)bf16rn(p10 * r1) | ((unsigned)bf16rn(p11 * r1) << 16);
        Pu[(base + (i0 & 15)) * 4 + eo] = w0;
        Pu[(base + ((i0 + 1) & 15)) * 4 + eo] = w1;
    }

    grid_bar(&bars[1]);

    // ---------------- Phase C: out[b] = P[b] @ h1[b] (MFMA, 16x16/wave) ---
    // 4096 wave-tasks: b x 32 i-tiles x 32 e-tiles. A-frags pre-packed.
    {
        const int wt = bid * 4 + wv;
        const int b = wt >> 10, rem = wt & 1023;
        const int it = rem >> 5, et = rem & 31;
        const float* __restrict__ hb = h1 + (size_t)b * S_ * E_ + et * 16 + l16;
        const bf16x8* __restrict__ Ab =
            (const bf16x8*)(Pp + (size_t)b * S_ * S_) + (it * 16) * 64 + lane;

        f32x4 acc = {0.f, 0.f, 0.f, 0.f};
        for (int kc = 0; kc < 16; ++kc) {
            const bf16x8 a8 = Ab[kc * 64];
            const int kb = kc * 32 + quad * 8;
            bf16x8 b8;
#pragma unroll
            for (int j = 0; j < 8; ++j)
                b8[j] = (short)bf16rn(hb[(size_t)(kb + j) * E_]);
            acc = __builtin_amdgcn_mfma_f32_16x16x32_bf16(a8, b8, acc, 0, 0, 0);
        }
        const int i = it * 16 + quad * 4;
        const int e = et * 16 + l16;
        float* __restrict__ ob = out + ((size_t)b * S_ + i) * E_ + e;
#pragma unroll
        for (int r = 0; r < 4; ++r)
            ob[(size_t)r * E_] = acc[r];
    }
}

extern "C" void kernel_launch(void* const* d_in, const int* in_sizes, int n_in,
                              void* d_out, int out_size, void* d_ws, size_t ws_size,
                              hipStream_t stream) {
    const float* h1 = (const float*)d_in[0];
    const float* h2 = (const float*)d_in[1];
    const float* w  = (const float*)d_in[2];
    const float* b1 = (const float*)d_in[3];
    const float* v  = (const float*)d_in[4];
    // d_in[5] = b2: cancels in softmax, unused.
    float* out = (float*)d_out;

    int* bars = (int*)d_ws;                                        // 2 slots
    float* keySt = (float*)((char*)d_ws + 256);                    // 2 MB
    float* qryS  = keySt + (size_t)B_ * U_ * S_;                   // 2 MB
    unsigned short* Pp = (unsigned short*)(qryS + (size_t)B_ * S_ * U_);  // 2 MB

    hipMemsetAsync(d_ws, 0, 256, stream);    // reset barrier slots每 call
    fused_attend<<<dim3(NBLK), dim3(256), 0, stream>>>(
        h1, h2, w, b1, v, out, keySt, qryS, Pp, bars);
}

// Round 7
// 382.523 us; speedup vs baseline: 1.3252x; 1.3252x over previous
//
#include <hip/hip_runtime.h>
#include <hip/hip_bf16.h>

#define B_ 4
#define S_ 512
#define E_ 512
#define U_ 256
#define NBLK 1024

// 2*log2(e): folded so tanh args feed exp2 directly: exp(2x) = exp2(KC*x)
#define KC 2.885390081777927f

#if __has_builtin(__builtin_amdgcn_exp2f)
#define EXP2F(x) __builtin_amdgcn_exp2f(x)
#else
#define EXP2F(x) __exp2f(x)
#endif
#if __has_builtin(__builtin_amdgcn_rcpf)
#define RCPF(x) __builtin_amdgcn_rcpf(x)
#else
#define RCPF(x) (1.0f / (x))
#endif

typedef __attribute__((ext_vector_type(8))) short bf16x8;
typedef __attribute__((ext_vector_type(4))) float f32x4;

__device__ __forceinline__ unsigned short bf16rn(float x) {
    unsigned int u = __float_as_uint(x);
    u = (u + 0x7FFFu + ((u >> 16) & 1u)) >> 16;   // RNE
    return (unsigned short)u;
}

// truncation split: x = hi + lo + O(2^-17 x); lo = x - hi is exact in fp32
__device__ __forceinline__ void splitT(float x, short* hi, short* lo) {
    const unsigned u = __float_as_uint(x);
    *hi = (short)(u >> 16);
    const float hf = __uint_as_float(u & 0xFFFF0000u);
    *lo = (short)(__float_as_uint(x - hf) >> 16);
}

// Device-scope grid barrier, RELAXED polling (the R6 version polled with an
// ACQUIRE load -> one full per-XCD L2 invalidate PER POLL ITERATION -> L2
// meltdown, 400us of stall). Fences only at the boundaries:
//   release fence (L2 writeback) once before arrival,
//   relaxed spin  (plain load, no cache maintenance),
//   acquire fence (one invalidate) once after release.
__device__ __forceinline__ void grid_bar(int* slot) {
    __syncthreads();
    if (threadIdx.x == 0) {
        __threadfence();   // release: prior writes -> coherence point
        __hip_atomic_fetch_add(slot, 1, __ATOMIC_RELAXED, __HIP_MEMORY_SCOPE_AGENT);
        while (__hip_atomic_load(slot, __ATOMIC_RELAXED, __HIP_MEMORY_SCOPE_AGENT) < NBLK)
            __builtin_amdgcn_s_sleep(8);
        __threadfence();   // acquire: drop stale lines once
    }
    __syncthreads();
}

// 4-way batched tanh-dot term: acc += sum_{q=0..3} v_q / F_q, F = exp2(arg)+1
__device__ __forceinline__ float quadTerm(float a0, float a1, float a2, float a3,
                                          float4 vq, float acc) {
    const float F1 = EXP2F(a0) + 1.f;
    const float F2 = EXP2F(a1) + 1.f;
    const float F3 = EXP2F(a2) + 1.f;
    const float F4 = EXP2F(a3) + 1.f;
    const float P12 = F1 * F2, P34 = F3 * F4;
    const float n12 = fmaf(vq.y, F1, vq.x * F2);
    const float n34 = fmaf(vq.w, F3, vq.z * F4);
    const float num = fmaf(n34, P12, n12 * P34);
    return fmaf(num, RCPF(P12 * P34), acc);
}

// ===========================================================================
// One kernel, three phases, two grid barriers. Grid MUST be exactly NBLK
// blocks of 256 thr; __launch_bounds__(256,4) caps VGPR<=128 so 4 blocks/CU
// (= NBLK/256CU) are co-resident -> software barrier cannot deadlock.
// ===========================================================================
__global__ void __launch_bounds__(256, 4)
fused_attend(const float* __restrict__ h1, const float* __restrict__ h2,
             const float* __restrict__ w, const float* __restrict__ b1,
             const float* __restrict__ v, float* __restrict__ out,
             float* __restrict__ keySt, float* __restrict__ qryS,
             unsigned short* __restrict__ Pp, int* __restrict__ bars)
{
    const int tid = threadIdx.x;
    const int bid = blockIdx.x;
    const int wv = tid >> 6, lane = tid & 63;
    const int quad = lane >> 4, l16 = lane & 15;

    __shared__ float ssm[4][2];

    // ---------------- Phase A: pre-GEMMs (MFMA hi/lo, 16x16 tile/wave) ----
    // 4096 wave-tasks: z (which projection) x 128 m-tiles x 16 n-tiles.
    //   z==0: keySt[b][u][j] = KC*(h1[b,j,:] @ w1[:,u])   (j contiguous)
    //   z==1: qryS [b][i][u] = KC*(h2[b,i,:] @ w2[:,u] + b1[u])
    {
        const int wt = bid * 4 + wv;
        const int z = wt >> 11, rem = wt & 2047;
        const int m0 = (rem >> 4) << 4, n0 = (rem & 15) << 4;
        const float* __restrict__ A = z ? h2 : h1;
        const float* __restrict__ Arow = A + (size_t)(m0 + l16) * E_;
        const float* __restrict__ Wcol = w + (size_t)z * E_ * U_ + n0 + l16;

        f32x4 acc = {0.f, 0.f, 0.f, 0.f};
        for (int kc = 0; kc < 16; ++kc) {
            const int kb = kc * 32 + quad * 8;
            const float4 x0 = *(const float4*)&Arow[kb];
            const float4 x1 = *(const float4*)&Arow[kb + 4];
            const float xs[8] = {x0.x, x0.y, x0.z, x0.w, x1.x, x1.y, x1.z, x1.w};
            bf16x8 ah, al;
#pragma unroll
            for (int j = 0; j < 8; ++j) {
                short h, l; splitT(xs[j], &h, &l);
                ah[j] = h; al[j] = l;
            }
            float ws8[8];
#pragma unroll
            for (int j = 0; j < 8; ++j)
                ws8[j] = Wcol[(size_t)(kb + j) * U_] * KC;
            bf16x8 wh, wl;
#pragma unroll
            for (int j = 0; j < 8; ++j) {
                short h, l; splitT(ws8[j], &h, &l);
                wh[j] = h; wl[j] = l;
            }
            acc = __builtin_amdgcn_mfma_f32_16x16x32_bf16(ah, wh, acc, 0, 0, 0);
            acc = __builtin_amdgcn_mfma_f32_16x16x32_bf16(ah, wl, acc, 0, 0, 0);
            acc = __builtin_amdgcn_mfma_f32_16x16x32_bf16(al, wh, acc, 0, 0, 0);
        }
        if (z == 0) {
            const int b = m0 >> 9;
            const int j0 = (m0 & (S_ - 1)) + quad * 4;     // C/D row = j
            const int u = n0 + l16;                        // C/D col = u
            *(float4*)&keySt[((size_t)b * U_ + u) * S_ + j0] =
                make_float4(acc[0], acc[1], acc[2], acc[3]);
        } else {
            const int row = m0 + quad * 4;
            const int u = n0 + l16;
            const float bias = KC * b1[u];
#pragma unroll
            for (int r = 0; r < 4; ++r)
                qryS[(size_t)(row + r) * U_ + u] = acc[r] + bias;
        }
    }

    grid_bar(&bars[0]);

    // ---------------- Phase B: scores + softmax -> packed bf16 P ----------
    // block <-> (b, 2 rows i); thread t <-> cols j = 2t, 2t+1.
    // a = sum_u v_u/(exp2(arg)+1); score = c - 2a (c, b2 cancel) ->
    // p = exp2(-a*KC), normalized. 1 rcp per 4 u via product batching.
    {
        const int b = bid >> 8;
        const int i0 = (bid & 255) << 1;
        const float* __restrict__ q0p = qryS + ((size_t)b * S_ + i0) * U_;
        const float4* __restrict__ q0v = (const float4*)q0p;
        const float4* __restrict__ q1v = (const float4*)(q0p + U_);
        const float4* __restrict__ vv4 = (const float4*)v;
        const float2* __restrict__ kb2 =
            (const float2*)(keySt + (size_t)b * U_ * S_) + tid;

        float a00 = 0.f, a01 = 0.f, a10 = 0.f, a11 = 0.f;
#pragma unroll 2
        for (int ub = 0; ub < U_ / 4; ++ub) {
            const float4 q0 = q0v[ub], q1 = q1v[ub], vq = vv4[ub];
            const float2 k0 = kb2[(ub * 4 + 0) * (S_ / 2)];
            const float2 k1 = kb2[(ub * 4 + 1) * (S_ / 2)];
            const float2 k2 = kb2[(ub * 4 + 2) * (S_ / 2)];
            const float2 k3 = kb2[(ub * 4 + 3) * (S_ / 2)];
            a00 = quadTerm(q0.x + k0.x, q0.y + k1.x, q0.z + k2.x, q0.w + k3.x, vq, a00);
            a01 = quadTerm(q0.x + k0.y, q0.y + k1.y, q0.z + k2.y, q0.w + k3.y, vq, a01);
            a10 = quadTerm(q1.x + k0.x, q1.y + k1.x, q1.z + k2.x, q1.w + k3.x, vq, a10);
            a11 = quadTerm(q1.x + k0.y, q1.y + k1.y, q1.z + k2.y, q1.w + k3.y, vq, a11);
        }

        // no max-shift needed: |a|*KC <= ~52, exp2 safe in fp32
        const float p00 = EXP2F(-a00 * KC), p01 = EXP2F(-a01 * KC);
        const float p10 = EXP2F(-a10 * KC), p11 = EXP2F(-a11 * KC);
        float s0 = p00 + p01, s1 = p10 + p11;
#pragma unroll
        for (int off = 1; off < 64; off <<= 1) {
            s0 += __shfl_xor(s0, off, 64);
            s1 += __shfl_xor(s1, off, 64);
        }
        if ((tid & 63) == 0) { ssm[wv][0] = s0; ssm[wv][1] = s1; }
        __syncthreads();
        s0 = (ssm[0][0] + ssm[1][0]) + (ssm[2][0] + ssm[3][0]);
        s1 = (ssm[0][1] + ssm[1][1]) + (ssm[2][1] + ssm[3][1]);
        const float r0 = RCPF(s0), r1 = RCPF(s1);

        // pack P into MFMA A-frag order:
        // slot = (itile*16 + (j>>5))*64 + ((i&15) | (((j>>3)&3)<<4)), elem j&7
        const int j2 = tid * 2;
        const int itile = i0 >> 4;
        const int base = (itile * 16 + (j2 >> 5)) * 64 + (((j2 >> 3) & 3) << 4);
        const int eo = tid & 3;                 // uint index inside slot
        unsigned* __restrict__ Pu = (unsigned*)(Pp + (size_t)b * S_ * S_);
        const unsigned w0 = (unsigned)bf16rn(p00 * r0) | ((unsigned)bf16rn(p01 * r0) << 16);
        const unsigned w1 = (unsigned)bf16rn(p10 * r1) | ((unsigned)bf16rn(p11 * r1) << 16);
        Pu[(base + (i0 & 15)) * 4 + eo] = w0;
        Pu[(base + ((i0 + 1) & 15)) * 4 + eo] = w1;
    }

    grid_bar(&bars[1]);

    // ---------------- Phase C: out[b] = P[b] @ h1[b] (MFMA, 16x16/wave) ---
    // 4096 wave-tasks: b x 32 i-tiles x 32 e-tiles. A-frags pre-packed.
    {
        const int wt = bid * 4 + wv;
        const int b = wt >> 10, rem = wt & 1023;
        const int it = rem >> 5, et = rem & 31;
        const float* __restrict__ hb = h1 + (size_t)b * S_ * E_ + et * 16 + l16;
        const bf16x8* __restrict__ Ab =
            (const bf16x8*)(Pp + (size_t)b * S_ * S_) + (it * 16) * 64 + lane;

        f32x4 acc = {0.f, 0.f, 0.f, 0.f};
        for (int kc = 0; kc < 16; ++kc) {
            const bf16x8 a8 = Ab[kc * 64];
            const int kb = kc * 32 + quad * 8;
            bf16x8 b8;
#pragma unroll
            for (int j = 0; j < 8; ++j)
                b8[j] = (short)bf16rn(hb[(size_t)(kb + j) * E_]);
            acc = __builtin_amdgcn_mfma_f32_16x16x32_bf16(a8, b8, acc, 0, 0, 0);
        }
        const int i = it * 16 + quad * 4;
        const int e = et * 16 + l16;
        float* __restrict__ ob = out + ((size_t)b * S_ + i) * E_ + e;
#pragma unroll
        for (int r = 0; r < 4; ++r)
            ob[(size_t)r * E_] = acc[r];
    }
}

extern "C" void kernel_launch(void* const* d_in, const int* in_sizes, int n_in,
                              void* d_out, int out_size, void* d_ws, size_t ws_size,
                              hipStream_t stream) {
    const float* h1 = (const float*)d_in[0];
    const float* h2 = (const float*)d_in[1];
    const float* w  = (const float*)d_in[2];
    const float* b1 = (const float*)d_in[3];
    const float* v  = (const float*)d_in[4];
    // d_in[5] = b2: cancels in softmax, unused.
    float* out = (float*)d_out;

    int* bars = (int*)d_ws;                                        // 2 slots
    float* keySt = (float*)((char*)d_ws + 256);                    // 2 MB
    float* qryS  = keySt + (size_t)B_ * U_ * S_;                   // 2 MB
    unsigned short* Pp = (unsigned short*)(qryS + (size_t)B_ * S_ * U_);  // 2 MB

    hipMemsetAsync(d_ws, 0, 256, stream);    // reset barrier slots per call
    fused_attend<<<dim3(NBLK), dim3(256), 0, stream>>>(
        h1, h2, w, b1, v, out, keySt, qryS, Pp, bars);
}

// Round 8
// 141.827 us; speedup vs baseline: 3.5741x; 2.6971x over previous
//
#include <hip/hip_runtime.h>
#include <hip/hip_bf16.h>

#define B_ 4
#define S_ 512
#define E_ 512
#define U_ 256

// 2*log2(e): folded so tanh args feed exp2 directly: exp(2x) = exp2(KC*x)
#define KC 2.885390081777927f

#if __has_builtin(__builtin_amdgcn_exp2f)
#define EXP2F(x) __builtin_amdgcn_exp2f(x)
#else
#define EXP2F(x) __exp2f(x)
#endif
#if __has_builtin(__builtin_amdgcn_rcpf)
#define RCPF(x) __builtin_amdgcn_rcpf(x)
#else
#define RCPF(x) (1.0f / (x))
#endif

typedef __attribute__((ext_vector_type(8))) short bf16x8;
typedef __attribute__((ext_vector_type(4))) float f32x4;

__device__ __forceinline__ unsigned short bf16rn(float x) {
    unsigned int u = __float_as_uint(x);
    u = (u + 0x7FFFu + ((u >> 16) & 1u)) >> 16;   // RNE
    return (unsigned short)u;
}
// truncation split: x = hi + lo (lo exact in fp32); dropped al*wl term ~2^-16
__device__ __forceinline__ void splitT(float x, short* hi, short* lo) {
    const unsigned u = __float_as_uint(x);
    *hi = (short)(u >> 16);
    const float hf = __uint_as_float(u & 0xFFFF0000u);
    *lo = (short)(__float_as_uint(x - hf) >> 16);
}

// ---------------------------------------------------------------------------
// prep: one-shot conversions into MFMA B-frag layouts (done ONCE, not per
// consumer wave as in R5 — that redundancy was the 87us residual).
//  W slots  (t < 32768):  whi/wlo[((z*16+nt)*16+kc)*64+lane] =
//       split(KC * w[z][kc*32+quad*8+j][nt*16+l16]),  j=0..7
//  h1 slots (t >= 32768): h1c[((b*32+et)*16+kc)*64+lane] =
//       bf16(h1[b][kc*32+quad*8+j][et*16+l16])
// grid 640x256 = 163840 threads, one slot each.
// ---------------------------------------------------------------------------
__global__ __launch_bounds__(256) void prep_kernel(
    const float* __restrict__ w, const float* __restrict__ h1,
    bf16x8* __restrict__ whi, bf16x8* __restrict__ wlo,
    bf16x8* __restrict__ h1c)
{
    const int t = blockIdx.x * 256 + threadIdx.x;
    if (t < 32768) {
        const int lane = t & 63, kc = (t >> 6) & 15, nt = (t >> 10) & 15, z = t >> 14;
        const int quad = lane >> 4, l16 = lane & 15;
        const float* __restrict__ src =
            w + (size_t)z * E_ * U_ + (size_t)(kc * 32 + quad * 8) * U_ + nt * 16 + l16;
        bf16x8 hi, lo;
#pragma unroll
        for (int j = 0; j < 8; ++j) {
            short h, l; splitT(src[(size_t)j * U_] * KC, &h, &l);
            hi[j] = h; lo[j] = l;
        }
        whi[t] = hi; wlo[t] = lo;
    } else {
        const int s = t - 32768;
        const int lane = s & 63, kc = (s >> 6) & 15, et = (s >> 10) & 31, b = s >> 15;
        const int quad = lane >> 4, l16 = lane & 15;
        const float* __restrict__ src =
            h1 + ((size_t)b * S_ + kc * 32 + quad * 8) * E_ + et * 16 + l16;
        bf16x8 c;
#pragma unroll
        for (int j = 0; j < 8; ++j)
            c[j] = (short)bf16rn(src[(size_t)j * E_]);
        h1c[s] = c;
    }
}

// ---------------------------------------------------------------------------
// gemm_pre: hi/lo MFMA, W-frags preconverted (coalesced dwordx4 reads).
// Wave-task wt = (z, mt 0..127, ng 0..3): 16 rows x 64 u, 4 accs.
//   z==0: keySt[b][u][j] = KC*(h1[b,j,:] @ w1[:,u])   (j contiguous)
//   z==1: qryS [b][i][u] = KC*(h2[b,i,:] @ w2[:,u] + b1[u])
// grid 256x256 = 1024 wave-tasks.
// ---------------------------------------------------------------------------
__global__ __launch_bounds__(256) void gemm_pre(
    const float* __restrict__ h1, const float* __restrict__ h2,
    const bf16x8* __restrict__ whi, const bf16x8* __restrict__ wlo,
    const float* __restrict__ b1,
    float* __restrict__ keySt, float* __restrict__ qryS)
{
    const int tid = threadIdx.x;
    const int wv = tid >> 6, lane = tid & 63;
    const int quad = lane >> 4, l16 = lane & 15;
    const int wt = blockIdx.x * 4 + wv;
    const int z = wt >> 9, rem = wt & 511;
    const int m0 = (rem >> 2) << 4;          // global row (b*S+s), 0..2047
    const int ng = rem & 3;                  // u-group: 4 n-tiles of 16

    const float* __restrict__ Arow = (z ? h2 : h1) + (size_t)(m0 + l16) * E_;
    const bf16x8* __restrict__ Wh = whi + ((z * 16 + ng * 4) * 16) * 64 + lane;
    const bf16x8* __restrict__ Wl = wlo + ((z * 16 + ng * 4) * 16) * 64 + lane;

    f32x4 acc[4];
#pragma unroll
    for (int i = 0; i < 4; ++i) acc[i] = (f32x4){0.f, 0.f, 0.f, 0.f};

    for (int kc = 0; kc < 16; ++kc) {
        const int kb = kc * 32 + quad * 8;
        const float4 x0 = *(const float4*)&Arow[kb];
        const float4 x1 = *(const float4*)&Arow[kb + 4];
        const float xs[8] = {x0.x, x0.y, x0.z, x0.w, x1.x, x1.y, x1.z, x1.w};
        bf16x8 ah, al;
#pragma unroll
        for (int j = 0; j < 8; ++j) {
            short h, l; splitT(xs[j], &h, &l);
            ah[j] = h; al[j] = l;
        }
#pragma unroll
        for (int nt = 0; nt < 4; ++nt) {
            const bf16x8 bh = Wh[(nt * 16 + kc) * 64];
            const bf16x8 bl = Wl[(nt * 16 + kc) * 64];
            acc[nt] = __builtin_amdgcn_mfma_f32_16x16x32_bf16(ah, bh, acc[nt], 0, 0, 0);
            acc[nt] = __builtin_amdgcn_mfma_f32_16x16x32_bf16(ah, bl, acc[nt], 0, 0, 0);
            acc[nt] = __builtin_amdgcn_mfma_f32_16x16x32_bf16(al, bh, acc[nt], 0, 0, 0);
        }
    }

    if (z == 0) {
        const int b = m0 >> 9;
        const int j0 = (m0 & (S_ - 1)) + quad * 4;       // C/D row = j
#pragma unroll
        for (int nt = 0; nt < 4; ++nt) {
            const int u = (ng * 4 + nt) * 16 + l16;      // C/D col = u
            *(float4*)&keySt[((size_t)b * U_ + u) * S_ + j0] =
                make_float4(acc[nt][0], acc[nt][1], acc[nt][2], acc[nt][3]);
        }
    } else {
        const int row = m0 + quad * 4;
#pragma unroll
        for (int nt = 0; nt < 4; ++nt) {
            const int u = (ng * 4 + nt) * 16 + l16;
            const float bias = KC * b1[u];
#pragma unroll
            for (int r = 0; r < 4; ++r)
                qryS[(size_t)(row + r) * U_ + u] = acc[nt][r] + bias;
        }
    }
}

// ---------------------------------------------------------------------------
// scores + softmax -> P packed in MFMA A-frag order (bf16).
// block <-> (b, 2 rows i); thread t <-> j = 2t, 2t+1. grid (256,4).
// a = sum_u v_u/(exp2(arg)+1); score = c - 2a (c, b2 cancel) ->
// p ~ exp2(-a*KC). 1 rcp per 4 u via product batching; no max-shift needed
// (|a*KC| <= ~52, exp2-safe).
// ---------------------------------------------------------------------------
__device__ __forceinline__ float quadTerm(float a0, float a1, float a2, float a3,
                                          float4 vq, float acc) {
    const float F1 = EXP2F(a0) + 1.f;
    const float F2 = EXP2F(a1) + 1.f;
    const float F3 = EXP2F(a2) + 1.f;
    const float F4 = EXP2F(a3) + 1.f;
    const float P12 = F1 * F2, P34 = F3 * F4;
    const float n12 = fmaf(vq.y, F1, vq.x * F2);
    const float n34 = fmaf(vq.w, F3, vq.z * F4);
    const float num = fmaf(n34, P12, n12 * P34);
    return fmaf(num, RCPF(P12 * P34), acc);
}

__global__ __launch_bounds__(256) void scores_kernel(
    const float* __restrict__ keySt, const float* __restrict__ qryS,
    const float* __restrict__ v, unsigned short* __restrict__ Pp)
{
    const int i0 = blockIdx.x * 2;
    const int b = blockIdx.y;
    const int tid = threadIdx.x;
    const int wv = tid >> 6;

    __shared__ float ssm[4][2];

    const float* __restrict__ q0p = qryS + ((size_t)b * S_ + i0) * U_;
    const float4* __restrict__ q0v = (const float4*)q0p;
    const float4* __restrict__ q1v = (const float4*)(q0p + U_);
    const float4* __restrict__ vv4 = (const float4*)v;
    const float2* __restrict__ kb2 =
        (const float2*)(keySt + (size_t)b * U_ * S_) + tid;

    float a00 = 0.f, a01 = 0.f, a10 = 0.f, a11 = 0.f;
#pragma unroll 2
    for (int ub = 0; ub < U_ / 4; ++ub) {
        const float4 q0 = q0v[ub], q1 = q1v[ub], vq = vv4[ub];
        const float2 k0 = kb2[(ub * 4 + 0) * (S_ / 2)];
        const float2 k1 = kb2[(ub * 4 + 1) * (S_ / 2)];
        const float2 k2 = kb2[(ub * 4 + 2) * (S_ / 2)];
        const float2 k3 = kb2[(ub * 4 + 3) * (S_ / 2)];
        a00 = quadTerm(q0.x + k0.x, q0.y + k1.x, q0.z + k2.x, q0.w + k3.x, vq, a00);
        a01 = quadTerm(q0.x + k0.y, q0.y + k1.y, q0.z + k2.y, q0.w + k3.y, vq, a01);
        a10 = quadTerm(q1.x + k0.x, q1.y + k1.x, q1.z + k2.x, q1.w + k3.x, vq, a10);
        a11 = quadTerm(q1.x + k0.y, q1.y + k1.y, q1.z + k2.y, q1.w + k3.y, vq, a11);
    }

    const float p00 = EXP2F(-a00 * KC), p01 = EXP2F(-a01 * KC);
    const float p10 = EXP2F(-a10 * KC), p11 = EXP2F(-a11 * KC);
    float s0 = p00 + p01, s1 = p10 + p11;
#pragma unroll
    for (int off = 1; off < 64; off <<= 1) {
        s0 += __shfl_xor(s0, off, 64);
        s1 += __shfl_xor(s1, off, 64);
    }
    if ((tid & 63) == 0) { ssm[wv][0] = s0; ssm[wv][1] = s1; }
    __syncthreads();
    s0 = (ssm[0][0] + ssm[1][0]) + (ssm[2][0] + ssm[3][0]);
    s1 = (ssm[0][1] + ssm[1][1]) + (ssm[2][1] + ssm[3][1]);
    const float r0 = RCPF(s0), r1 = RCPF(s1);

    // pack into A-frag order: slot = (it*16 + j/32)*64 + (quad(j)*16 | i&15)
    const int j2 = tid * 2;
    const int itile = i0 >> 4;
    const int base = (itile * 16 + (j2 >> 5)) * 64 + (((j2 >> 3) & 3) << 4);
    const int eo = tid & 3;
    unsigned* __restrict__ Pu = (unsigned*)(Pp + (size_t)b * S_ * S_);
    const unsigned w0 = (unsigned)bf16rn(p00 * r0) | ((unsigned)bf16rn(p01 * r0) << 16);
    const unsigned w1 = (unsigned)bf16rn(p10 * r1) | ((unsigned)bf16rn(p11 * r1) << 16);
    Pu[(base + (i0 & 15)) * 4 + eo] = w0;
    Pu[(base + ((i0 + 1) & 15)) * 4 + eo] = w1;
}

// ---------------------------------------------------------------------------
// pv: out[b] = P[b] @ h1[b]; A-frags pre-packed by scores, B-frags
// preconverted by prep. Wave-task (b, it 0..31, eg 0..7): 16 i x 64 e.
// grid 256x256 = 1024 wave-tasks. Pure loads + MFMA.
// ---------------------------------------------------------------------------
__global__ __launch_bounds__(256) void pv_gemm(
    const unsigned short* __restrict__ Pp, const bf16x8* __restrict__ h1c,
    float* __restrict__ out)
{
    const int tid = threadIdx.x;
    const int wv = tid >> 6, lane = tid & 63;
    const int quad = lane >> 4, l16 = lane & 15;
    const int wt = blockIdx.x * 4 + wv;
    const int b = wt >> 8, rem = wt & 255;
    const int it = rem >> 3, eg = rem & 7;

    const bf16x8* __restrict__ Ab =
        (const bf16x8*)(Pp + (size_t)b * S_ * S_) + (it * 16) * 64 + lane;
    const bf16x8* __restrict__ Bb =
        h1c + ((b * 32 + eg * 4) * 16) * 64 + lane;

    f32x4 acc[4];
#pragma unroll
    for (int i = 0; i < 4; ++i) acc[i] = (f32x4){0.f, 0.f, 0.f, 0.f};

    for (int kc = 0; kc < 16; ++kc) {
        const bf16x8 a8 = Ab[kc * 64];
#pragma unroll
        for (int n = 0; n < 4; ++n) {
            const bf16x8 b8 = Bb[(n * 16 + kc) * 64];
            acc[n] = __builtin_amdgcn_mfma_f32_16x16x32_bf16(a8, b8, acc[n], 0, 0, 0);
        }
    }

    const int i = it * 16 + quad * 4;
#pragma unroll
    for (int n = 0; n < 4; ++n) {
        const int e = (eg * 4 + n) * 16 + l16;
        float* __restrict__ ob = out + ((size_t)b * S_ + i) * E_ + e;
#pragma unroll
        for (int r = 0; r < 4; ++r)
            ob[(size_t)r * E_] = acc[n][r];
    }
}

extern "C" void kernel_launch(void* const* d_in, const int* in_sizes, int n_in,
                              void* d_out, int out_size, void* d_ws, size_t ws_size,
                              hipStream_t stream) {
    const float* h1 = (const float*)d_in[0];
    const float* h2 = (const float*)d_in[1];
    const float* w  = (const float*)d_in[2];
    const float* b1 = (const float*)d_in[3];
    const float* v  = (const float*)d_in[4];
    // d_in[5] = b2: cancels in softmax, unused.
    float* out = (float*)d_out;

    char* ws = (char*)d_ws;
    float* keySt = (float*)ws;                               ws += 2u << 20;  // 2 MB
    float* qryS  = (float*)ws;                               ws += 2u << 20;  // 2 MB
    unsigned short* Pp = (unsigned short*)ws;                ws += 2u << 20;  // 2 MB
    bf16x8* whi = (bf16x8*)ws;                               ws += 512u << 10; // 512 KB
    bf16x8* wlo = (bf16x8*)ws;                               ws += 512u << 10; // 512 KB
    bf16x8* h1c = (bf16x8*)ws;                                                // 2 MB

    prep_kernel<<<dim3(640), dim3(256), 0, stream>>>(w, h1, whi, wlo, h1c);
    gemm_pre<<<dim3(256), dim3(256), 0, stream>>>(h1, h2, whi, wlo, b1, keySt, qryS);
    scores_kernel<<<dim3(S_ / 2, B_), dim3(256), 0, stream>>>(keySt, qryS, v, Pp);
    pv_gemm<<<dim3(256), dim3(256), 0, stream>>>(Pp, h1c, out);
}

// Round 9
// 139.572 us; speedup vs baseline: 3.6319x; 1.0162x over previous
//
#include <hip/hip_runtime.h>
#include <hip/hip_bf16.h>

#define B_ 4
#define S_ 512
#define E_ 512
#define U_ 256

// 2*log2(e): folded so tanh args feed exp2 directly: exp(2x) = exp2(KC*x)
#define KC 2.885390081777927f

#if __has_builtin(__builtin_amdgcn_exp2f)
#define EXP2F(x) __builtin_amdgcn_exp2f(x)
#else
#define EXP2F(x) __exp2f(x)
#endif
#if __has_builtin(__builtin_amdgcn_rcpf)
#define RCPF(x) __builtin_amdgcn_rcpf(x)
#else
#define RCPF(x) (1.0f / (x))
#endif

typedef __attribute__((ext_vector_type(8))) short bf16x8;
typedef __attribute__((ext_vector_type(4))) float f32x4;

__device__ __forceinline__ unsigned short bf16rn(float x) {
    unsigned int u = __float_as_uint(x);
    u = (u + 0x7FFFu + ((u >> 16) & 1u)) >> 16;   // RNE
    return (unsigned short)u;
}
// truncation split: x = hi + lo (lo exact in fp32); dropped lo*lo term ~2^-16
__device__ __forceinline__ void splitT(float x, short* hi, short* lo) {
    const unsigned u = __float_as_uint(x);
    *hi = (short)(u >> 16);
    const float hf = __uint_as_float(u & 0xFFFF0000u);
    *lo = (short)(__float_as_uint(x - hf) >> 16);
}

// ---------------------------------------------------------------------------
// Kernel 1 (dual role, 1024 blocks x 256 thr):
//  blocks 0..511  — pre-GEMMs. block <-> (z, ngg 0..7 = 32-u slab, mq 0..31).
//    Step 1: 4 waves cooperatively convert W slab (512k x 32u, xKC, hi/lo
//            split) into LDS in MFMA B-frag order (coalesced global reads).
//    Step 2: wave w computes m-tile mq*4+w (16 rows x 32 u) with 3-MFMA
//            hi/lo per frag pair; frag reads are ds_read_b128.
//      z==0: keySt[b][u][j] = KC*(h1[b,j,:] @ w1[:,u])    (j contiguous)
//      z==1: qryS [b][i][u] = KC*(h2[b,i,:] @ w2[:,u] + b1[u])
//  blocks 512..1023 — cast h1 -> h1c in MFMA B-frag order (for pv):
//    h1c[((b*32+et)*16+kc)*64+lane] = bf16(h1[b][kc*32+quad*8+j][et*16+l16])
// ---------------------------------------------------------------------------
__global__ __launch_bounds__(256) void prep_gemm(
    const float* __restrict__ h1, const float* __restrict__ h2,
    const float* __restrict__ w, const float* __restrict__ b1,
    float* __restrict__ keySt, float* __restrict__ qryS,
    bf16x8* __restrict__ h1c)
{
    __shared__ unsigned short WhiL[2][16][64][8];   // [nt][kc][lane][j] 32 KB
    __shared__ unsigned short WloL[2][16][64][8];   // 32 KB

    const int tid = threadIdx.x;
    const int bid = blockIdx.x;

    if (bid < 512) {
        const int z = bid >> 8, ngg = (bid >> 5) & 7, mq = bid & 31;

        // ---- W slab conversion: rows k, 32 consecutive u (coalesced) ----
        const int r8 = tid >> 5, ul = tid & 31;
        const int ntc = ul >> 4, l16c = ul & 15;
        const float* __restrict__ Wp = w + (size_t)z * E_ * U_ + ngg * 32 + ul;
#pragma unroll 4
        for (int it = 0; it < 64; ++it) {
            const int k = it * 8 + r8;
            short h, l;
            splitT(Wp[(size_t)k * U_] * KC, &h, &l);
            const int kc = k >> 5, quad = (k >> 3) & 3, jj = k & 7;
            WhiL[ntc][kc][quad * 16 + l16c][jj] = (unsigned short)h;
            WloL[ntc][kc][quad * 16 + l16c][jj] = (unsigned short)l;
        }
        __syncthreads();

        // ---- MFMA main loop: one 16-row m-tile per wave ----
        const int wv = tid >> 6, lane = tid & 63;
        const int quad = lane >> 4, l16 = lane & 15;
        const int m0 = (mq * 4 + wv) * 16;
        const float* __restrict__ Arow = (z ? h2 : h1) + (size_t)(m0 + l16) * E_;

        f32x4 acc[2];
        acc[0] = (f32x4){0.f, 0.f, 0.f, 0.f};
        acc[1] = (f32x4){0.f, 0.f, 0.f, 0.f};

        for (int kc = 0; kc < 16; ++kc) {
            const int kb = kc * 32 + quad * 8;
            const float4 x0 = *(const float4*)&Arow[kb];
            const float4 x1 = *(const float4*)&Arow[kb + 4];
            const float xs[8] = {x0.x, x0.y, x0.z, x0.w, x1.x, x1.y, x1.z, x1.w};
            bf16x8 ah, al;
#pragma unroll
            for (int j = 0; j < 8; ++j) {
                short h, l; splitT(xs[j], &h, &l);
                ah[j] = h; al[j] = l;
            }
#pragma unroll
            for (int nt = 0; nt < 2; ++nt) {
                const bf16x8 bh = *(const bf16x8*)&WhiL[nt][kc][lane][0];
                const bf16x8 bl = *(const bf16x8*)&WloL[nt][kc][lane][0];
                acc[nt] = __builtin_amdgcn_mfma_f32_16x16x32_bf16(ah, bh, acc[nt], 0, 0, 0);
                acc[nt] = __builtin_amdgcn_mfma_f32_16x16x32_bf16(ah, bl, acc[nt], 0, 0, 0);
                acc[nt] = __builtin_amdgcn_mfma_f32_16x16x32_bf16(al, bh, acc[nt], 0, 0, 0);
            }
        }

        if (z == 0) {
            const int b = m0 >> 9;
            const int j0 = (m0 & (S_ - 1)) + quad * 4;       // C/D row = j
#pragma unroll
            for (int nt = 0; nt < 2; ++nt) {
                const int u = (ngg * 2 + nt) * 16 + l16;     // C/D col = u
                *(float4*)&keySt[((size_t)b * U_ + u) * S_ + j0] =
                    make_float4(acc[nt][0], acc[nt][1], acc[nt][2], acc[nt][3]);
            }
        } else {
            const int row = m0 + quad * 4;
#pragma unroll
            for (int nt = 0; nt < 2; ++nt) {
                const int u = (ngg * 2 + nt) * 16 + l16;
                const float bias = KC * b1[u];
#pragma unroll
                for (int r = 0; r < 4; ++r)
                    qryS[(size_t)(row + r) * U_ + u] = acc[nt][r] + bias;
            }
        }
    } else {
        // ---- h1 -> bf16 B-frag cast for pv ----
        const int s = (bid - 512) * 256 + tid;
        const int lane = s & 63, kc = (s >> 6) & 15, et = (s >> 10) & 31, b = s >> 15;
        const int quad = lane >> 4, l16 = lane & 15;
        const float* __restrict__ src =
            h1 + ((size_t)b * S_ + kc * 32 + quad * 8) * E_ + et * 16 + l16;
        bf16x8 c;
#pragma unroll
        for (int j = 0; j < 8; ++j)
            c[j] = (short)bf16rn(src[(size_t)j * E_]);
        h1c[s] = c;
    }
}

// ---------------------------------------------------------------------------
// scores + softmax -> P packed in MFMA A-frag order (bf16).
// 512 thr/block, thread t <-> column j = t, 2 query rows per block.
// grid (256, 4) = 1024 blocks x 8 waves = 32 waves/CU (vs 16 in R8 — the
// measured stall was L2-load latency at low TLP).
// a = sum_u v_u/(exp2(arg)+1); score = c - 2a (c, b2 cancel) ->
// p ~ exp2(-a*KC), normalized; |a*KC| <= ~52 so no max-shift needed.
// 1 rcp per 4 u via product batching (trans/elem = 1.25).
// ---------------------------------------------------------------------------
__device__ __forceinline__ float quadTerm(float a0, float a1, float a2, float a3,
                                          float4 vq, float acc) {
    const float F1 = EXP2F(a0) + 1.f;
    const float F2 = EXP2F(a1) + 1.f;
    const float F3 = EXP2F(a2) + 1.f;
    const float F4 = EXP2F(a3) + 1.f;
    const float P12 = F1 * F2, P34 = F3 * F4;
    const float n12 = fmaf(vq.y, F1, vq.x * F2);
    const float n34 = fmaf(vq.w, F3, vq.z * F4);
    const float num = fmaf(n34, P12, n12 * P34);
    return fmaf(num, RCPF(P12 * P34), acc);
}

__global__ __launch_bounds__(512) void scores_kernel(
    const float* __restrict__ keySt, const float* __restrict__ qryS,
    const float* __restrict__ v, unsigned short* __restrict__ Pp)
{
    const int i0 = blockIdx.x * 2;
    const int b = blockIdx.y;
    const int t = threadIdx.x;          // j = t
    const int wv = t >> 6;

    __shared__ float ssm[8][2];

    const float* __restrict__ q0p = qryS + ((size_t)b * S_ + i0) * U_;
    const float4* __restrict__ q0v = (const float4*)q0p;
    const float4* __restrict__ q1v = (const float4*)(q0p + U_);
    const float4* __restrict__ vv4 = (const float4*)v;
    const float* __restrict__ kb = keySt + (size_t)b * U_ * S_ + t;

    float a0 = 0.f, a1 = 0.f;
#pragma unroll 4
    for (int ub = 0; ub < U_ / 4; ++ub) {
        const float4 q0 = q0v[ub], q1 = q1v[ub], vq = vv4[ub];   // uniform -> SGPR
        const float k0 = kb[(size_t)(ub * 4 + 0) * S_];
        const float k1 = kb[(size_t)(ub * 4 + 1) * S_];
        const float k2 = kb[(size_t)(ub * 4 + 2) * S_];
        const float k3 = kb[(size_t)(ub * 4 + 3) * S_];
        a0 = quadTerm(q0.x + k0, q0.y + k1, q0.z + k2, q0.w + k3, vq, a0);
        a1 = quadTerm(q1.x + k0, q1.y + k1, q1.z + k2, q1.w + k3, vq, a1);
    }

    const float p0 = EXP2F(-a0 * KC);
    const float p1 = EXP2F(-a1 * KC);
    float s0 = p0, s1 = p1;
#pragma unroll
    for (int off = 1; off < 64; off <<= 1) {
        s0 += __shfl_xor(s0, off, 64);
        s1 += __shfl_xor(s1, off, 64);
    }
    if ((t & 63) == 0) { ssm[wv][0] = s0; ssm[wv][1] = s1; }
    __syncthreads();
    s0 = ssm[0][0]; s1 = ssm[0][1];
#pragma unroll
    for (int k = 1; k < 8; ++k) { s0 += ssm[k][0]; s1 += ssm[k][1]; }
    const float r0 = RCPF(s0), r1 = RCPF(s1);

    // pack into A-frag order: slot = (it*16 + j/32)*64 + quad(j)*16 + (i&15),
    // halfword j&7 inside the slot. Consecutive j -> consecutive halfwords.
    const int itile = i0 >> 4;
    const int base = (itile * 16 + (t >> 5)) * 64 + (((t >> 3) & 3) << 4);
    unsigned short* __restrict__ pb = Pp + (size_t)b * S_ * S_;
    pb[((base + (i0 & 15)) << 3) + (t & 7)] = bf16rn(p0 * r0);
    pb[((base + ((i0 + 1) & 15)) << 3) + (t & 7)] = bf16rn(p1 * r1);
}

// ---------------------------------------------------------------------------
// pv: out[b] = P[b] @ h1[b]; A-frags pre-packed by scores, B-frags (h1c)
// by prep_gemm. Wave-task (b, it 0..31, eg 0..7): 16 i x 64 e.
// grid 256x256 = 1024 wave-tasks. Pure coalesced loads + MFMA.
// ---------------------------------------------------------------------------
__global__ __launch_bounds__(256) void pv_gemm(
    const unsigned short* __restrict__ Pp, const bf16x8* __restrict__ h1c,
    float* __restrict__ out)
{
    const int tid = threadIdx.x;
    const int wv = tid >> 6, lane = tid & 63;
    const int quad = lane >> 4, l16 = lane & 15;
    const int wt = blockIdx.x * 4 + wv;
    const int b = wt >> 8, rem = wt & 255;
    const int it = rem >> 3, eg = rem & 7;

    const bf16x8* __restrict__ Ab =
        (const bf16x8*)(Pp + (size_t)b * S_ * S_) + (it * 16) * 64 + lane;
    const bf16x8* __restrict__ Bb =
        h1c + ((b * 32 + eg * 4) * 16) * 64 + lane;

    f32x4 acc[4];
#pragma unroll
    for (int i = 0; i < 4; ++i) acc[i] = (f32x4){0.f, 0.f, 0.f, 0.f};

    for (int kc = 0; kc < 16; ++kc) {
        const bf16x8 a8 = Ab[kc * 64];
#pragma unroll
        for (int n = 0; n < 4; ++n) {
            const bf16x8 b8 = Bb[(n * 16 + kc) * 64];
            acc[n] = __builtin_amdgcn_mfma_f32_16x16x32_bf16(a8, b8, acc[n], 0, 0, 0);
        }
    }

    const int i = it * 16 + quad * 4;
#pragma unroll
    for (int n = 0; n < 4; ++n) {
        const int e = (eg * 4 + n) * 16 + l16;
        float* __restrict__ ob = out + ((size_t)b * S_ + i) * E_ + e;
#pragma unroll
        for (int r = 0; r < 4; ++r)
            ob[(size_t)r * E_] = acc[n][r];
    }
}

extern "C" void kernel_launch(void* const* d_in, const int* in_sizes, int n_in,
                              void* d_out, int out_size, void* d_ws, size_t ws_size,
                              hipStream_t stream) {
    const float* h1 = (const float*)d_in[0];
    const float* h2 = (const float*)d_in[1];
    const float* w  = (const float*)d_in[2];
    const float* b1 = (const float*)d_in[3];
    const float* v  = (const float*)d_in[4];
    // d_in[5] = b2: cancels in softmax, unused.
    float* out = (float*)d_out;

    char* ws = (char*)d_ws;
    float* keySt = (float*)ws;                 ws += 2u << 20;  // 2 MB
    float* qryS  = (float*)ws;                 ws += 2u << 20;  // 2 MB
    unsigned short* Pp = (unsigned short*)ws;  ws += 2u << 20;  // 2 MB
    bf16x8* h1c = (bf16x8*)ws;                                  // 2 MB

    prep_gemm<<<dim3(1024), dim3(256), 0, stream>>>(h1, h2, w, b1, keySt, qryS, h1c);
    scores_kernel<<<dim3(S_ / 2, B_), dim3(512), 0, stream>>>(keySt, qryS, v, Pp);
    pv_gemm<<<dim3(256), dim3(256), 0, stream>>>(Pp, h1c, out);
}

// Round 10
// 137.776 us; speedup vs baseline: 3.6792x; 1.0130x over previous
//
#include <hip/hip_runtime.h>
#include <hip/hip_bf16.h>

#define B_ 4
#define S_ 512
#define E_ 512
#define U_ 256

// 2*log2(e): folded so tanh args feed exp2 directly: exp(2x) = exp2(KC*x)
#define KC 2.885390081777927f

#if __has_builtin(__builtin_amdgcn_exp2f)
#define EXP2F(x) __builtin_amdgcn_exp2f(x)
#else
#define EXP2F(x) __exp2f(x)
#endif
#if __has_builtin(__builtin_amdgcn_rcpf)
#define RCPF(x) __builtin_amdgcn_rcpf(x)
#else
#define RCPF(x) (1.0f / (x))
#endif

typedef __attribute__((ext_vector_type(8))) short bf16x8;
typedef __attribute__((ext_vector_type(4))) float f32x4;

__device__ __forceinline__ unsigned short bf16rn(float x) {
    unsigned int u = __float_as_uint(x);
    u = (u + 0x7FFFu + ((u >> 16) & 1u)) >> 16;   // RNE
    return (unsigned short)u;
}
// truncation split: x = hi + lo (lo exact in fp32); dropped lo*lo term ~2^-16
__device__ __forceinline__ void splitT(float x, short* hi, short* lo) {
    const unsigned u = __float_as_uint(x);
    *hi = (short)(u >> 16);
    const float hf = __uint_as_float(u & 0xFFFF0000u);
    *lo = (short)(__float_as_uint(x - hf) >> 16);
}

// ---------------------------------------------------------------------------
// Kernel 1 (dual role, 1024 blocks x 256 thr) — unchanged from R9.
//  blocks 0..511  — pre-GEMMs. block <-> (z, ngg 0..7 = 32-u slab, mq 0..31).
//    4 waves convert the W slab (coalesced) into LDS B-frag hi/lo, then each
//    wave computes one 16-row m-tile (16r x 32u) with 3-MFMA hi/lo.
//      z==0: keySt[b][u][j] = KC*(h1[b,j,:] @ w1[:,u])    (j contiguous)
//      z==1: qryS [b][i][u] = KC*(h2[b,i,:] @ w2[:,u] + b1[u])
//  blocks 512..1023 — cast h1 -> h1c in MFMA B-frag order (for pv).
// ---------------------------------------------------------------------------
__global__ __launch_bounds__(256) void prep_gemm(
    const float* __restrict__ h1, const float* __restrict__ h2,
    const float* __restrict__ w, const float* __restrict__ b1,
    float* __restrict__ keySt, float* __restrict__ qryS,
    bf16x8* __restrict__ h1c)
{
    __shared__ unsigned short WhiL[2][16][64][8];   // [nt][kc][lane][j] 32 KB
    __shared__ unsigned short WloL[2][16][64][8];   // 32 KB

    const int tid = threadIdx.x;
    const int bid = blockIdx.x;

    if (bid < 512) {
        const int z = bid >> 8, ngg = (bid >> 5) & 7, mq = bid & 31;

        // ---- W slab conversion (coalesced rows of 32 u) ----
        const int r8 = tid >> 5, ul = tid & 31;
        const int ntc = ul >> 4, l16c = ul & 15;
        const float* __restrict__ Wp = w + (size_t)z * E_ * U_ + ngg * 32 + ul;
#pragma unroll 4
        for (int it = 0; it < 64; ++it) {
            const int k = it * 8 + r8;
            short h, l;
            splitT(Wp[(size_t)k * U_] * KC, &h, &l);
            const int kc = k >> 5, quad = (k >> 3) & 3, jj = k & 7;
            WhiL[ntc][kc][quad * 16 + l16c][jj] = (unsigned short)h;
            WloL[ntc][kc][quad * 16 + l16c][jj] = (unsigned short)l;
        }
        __syncthreads();

        // ---- MFMA main loop: one 16-row m-tile per wave ----
        const int wv = tid >> 6, lane = tid & 63;
        const int quad = lane >> 4, l16 = lane & 15;
        const int m0 = (mq * 4 + wv) * 16;
        const float* __restrict__ Arow = (z ? h2 : h1) + (size_t)(m0 + l16) * E_;

        f32x4 acc[2];
        acc[0] = (f32x4){0.f, 0.f, 0.f, 0.f};
        acc[1] = (f32x4){0.f, 0.f, 0.f, 0.f};

        for (int kc = 0; kc < 16; ++kc) {
            const int kb = kc * 32 + quad * 8;
            const float4 x0 = *(const float4*)&Arow[kb];
            const float4 x1 = *(const float4*)&Arow[kb + 4];
            const float xs[8] = {x0.x, x0.y, x0.z, x0.w, x1.x, x1.y, x1.z, x1.w};
            bf16x8 ah, al;
#pragma unroll
            for (int j = 0; j < 8; ++j) {
                short h, l; splitT(xs[j], &h, &l);
                ah[j] = h; al[j] = l;
            }
#pragma unroll
            for (int nt = 0; nt < 2; ++nt) {
                const bf16x8 bh = *(const bf16x8*)&WhiL[nt][kc][lane][0];
                const bf16x8 bl = *(const bf16x8*)&WloL[nt][kc][lane][0];
                acc[nt] = __builtin_amdgcn_mfma_f32_16x16x32_bf16(ah, bh, acc[nt], 0, 0, 0);
                acc[nt] = __builtin_amdgcn_mfma_f32_16x16x32_bf16(ah, bl, acc[nt], 0, 0, 0);
                acc[nt] = __builtin_amdgcn_mfma_f32_16x16x32_bf16(al, bh, acc[nt], 0, 0, 0);
            }
        }

        if (z == 0) {
            const int b = m0 >> 9;
            const int j0 = (m0 & (S_ - 1)) + quad * 4;       // C/D row = j
#pragma unroll
            for (int nt = 0; nt < 2; ++nt) {
                const int u = (ngg * 2 + nt) * 16 + l16;     // C/D col = u
                *(float4*)&keySt[((size_t)b * U_ + u) * S_ + j0] =
                    make_float4(acc[nt][0], acc[nt][1], acc[nt][2], acc[nt][3]);
            }
        } else {
            const int row = m0 + quad * 4;
#pragma unroll
            for (int nt = 0; nt < 2; ++nt) {
                const int u = (ngg * 2 + nt) * 16 + l16;
                const float bias = KC * b1[u];
#pragma unroll
                for (int r = 0; r < 4; ++r)
                    qryS[(size_t)(row + r) * U_ + u] = acc[nt][r] + bias;
            }
        }
    } else {
        // ---- h1 -> bf16 B-frag cast for pv ----
        const int s = (bid - 512) * 256 + tid;
        const int lane = s & 63, kc = (s >> 6) & 15, et = (s >> 10) & 31, b = s >> 15;
        const int quad = lane >> 4, l16 = lane & 15;
        const float* __restrict__ src =
            h1 + ((size_t)b * S_ + kc * 32 + quad * 8) * E_ + et * 16 + l16;
        bf16x8 c;
#pragma unroll
        for (int j = 0; j < 8; ++j)
            c[j] = (short)bf16rn(src[(size_t)j * E_]);
        h1c[s] = c;
    }
}

// ---------------------------------------------------------------------------
// scores + softmax -> P packed in MFMA A-frag order (bf16).
// TI=4: 512 thr/block, thread t <-> column j = t, FOUR query rows per block.
// grid (128, 4) = 512 blocks x 8 waves = 2 blocks/CU — all resident at t=0.
// 4 independent accumulator chains per thread (R9 had 2): the measured stall
// was dependency-chain latency (waves issuing 1 instr / ~6 cyc), not TLP.
// k-loads amortized over 4 rows (0.25 loads/element).
// a = sum_u v_u/(exp2(arg)+1); score = c - 2a (c, b2 cancel) ->
// p ~ exp2(-a*KC); |a*KC| <= ~52 so no max-shift needed.
// ---------------------------------------------------------------------------
__device__ __forceinline__ float quadTerm(float a0, float a1, float a2, float a3,
                                          float4 vq, float acc) {
    const float F1 = EXP2F(a0) + 1.f;
    const float F2 = EXP2F(a1) + 1.f;
    const float F3 = EXP2F(a2) + 1.f;
    const float F4 = EXP2F(a3) + 1.f;
    const float P12 = F1 * F2, P34 = F3 * F4;
    const float n12 = fmaf(vq.y, F1, vq.x * F2);
    const float n34 = fmaf(vq.w, F3, vq.z * F4);
    const float num = fmaf(n34, P12, n12 * P34);
    return fmaf(num, RCPF(P12 * P34), acc);
}

__global__ __launch_bounds__(512) void scores_kernel(
    const float* __restrict__ keySt, const float* __restrict__ qryS,
    const float* __restrict__ v, unsigned short* __restrict__ Pp)
{
    const int i0 = blockIdx.x * 4;
    const int b = blockIdx.y;
    const int t = threadIdx.x;          // j = t
    const int wv = t >> 6;

    __shared__ float ssm[8][4];

    const float4* __restrict__ q0v = (const float4*)(qryS + ((size_t)b * S_ + i0) * U_);
    const float4* __restrict__ q1v = q0v + (U_ / 4);
    const float4* __restrict__ q2v = q0v + 2 * (U_ / 4);
    const float4* __restrict__ q3v = q0v + 3 * (U_ / 4);
    const float4* __restrict__ vv4 = (const float4*)v;
    const float* __restrict__ kb = keySt + (size_t)b * U_ * S_ + t;

    float a0 = 0.f, a1 = 0.f, a2 = 0.f, a3 = 0.f;
#pragma unroll 4
    for (int ub = 0; ub < U_ / 4; ++ub) {
        const float4 vq = vv4[ub];                     // uniform -> SGPR
        const float k0 = kb[(size_t)(ub * 4 + 0) * S_];
        const float k1 = kb[(size_t)(ub * 4 + 1) * S_];
        const float k2 = kb[(size_t)(ub * 4 + 2) * S_];
        const float k3 = kb[(size_t)(ub * 4 + 3) * S_];
        const float4 q0 = q0v[ub], q1 = q1v[ub], q2 = q2v[ub], q3 = q3v[ub];
        a0 = quadTerm(q0.x + k0, q0.y + k1, q0.z + k2, q0.w + k3, vq, a0);
        a1 = quadTerm(q1.x + k0, q1.y + k1, q1.z + k2, q1.w + k3, vq, a1);
        a2 = quadTerm(q2.x + k0, q2.y + k1, q2.z + k2, q2.w + k3, vq, a2);
        a3 = quadTerm(q3.x + k0, q3.y + k1, q3.z + k2, q3.w + k3, vq, a3);
    }

    const float p0 = EXP2F(-a0 * KC);
    const float p1 = EXP2F(-a1 * KC);
    const float p2 = EXP2F(-a2 * KC);
    const float p3 = EXP2F(-a3 * KC);
    float s0 = p0, s1 = p1, s2 = p2, s3 = p3;
#pragma unroll
    for (int off = 1; off < 64; off <<= 1) {
        s0 += __shfl_xor(s0, off, 64);
        s1 += __shfl_xor(s1, off, 64);
        s2 += __shfl_xor(s2, off, 64);
        s3 += __shfl_xor(s3, off, 64);
    }
    if ((t & 63) == 0) {
        ssm[wv][0] = s0; ssm[wv][1] = s1; ssm[wv][2] = s2; ssm[wv][3] = s3;
    }
    __syncthreads();
    s0 = ssm[0][0]; s1 = ssm[0][1]; s2 = ssm[0][2]; s3 = ssm[0][3];
#pragma unroll
    for (int k = 1; k < 8; ++k) {
        s0 += ssm[k][0]; s1 += ssm[k][1]; s2 += ssm[k][2]; s3 += ssm[k][3];
    }
    const float r0 = RCPF(s0), r1 = RCPF(s1), r2 = RCPF(s2), r3 = RCPF(s3);

    // pack into A-frag order: slot = (it*16 + j/32)*64 + quad(j)*16 + (i&15),
    // halfword j&7. i0 = 4*blockIdx.x -> rows stay inside one 16-block.
    const int itile = i0 >> 4;
    const int base = (itile * 16 + (t >> 5)) * 64 + (((t >> 3) & 3) << 4);
    unsigned short* __restrict__ pb = Pp + (size_t)b * S_ * S_;
    const int io = i0 & 15, jo = t & 7;
    pb[((base + io + 0) << 3) + jo] = bf16rn(p0 * r0);
    pb[((base + io + 1) << 3) + jo] = bf16rn(p1 * r1);
    pb[((base + io + 2) << 3) + jo] = bf16rn(p2 * r2);
    pb[((base + io + 3) << 3) + jo] = bf16rn(p3 * r3);
}

// ---------------------------------------------------------------------------
// pv: out[b] = P[b] @ h1[b]; A-frags pre-packed by scores, B-frags (h1c)
// by prep_gemm. Wave-task (b, it 0..31, eg 0..7): 16 i x 64 e.
// grid 256x256 = 1024 wave-tasks. Pure coalesced loads + MFMA. (unchanged)
// ---------------------------------------------------------------------------
__global__ __launch_bounds__(256) void pv_gemm(
    const unsigned short* __restrict__ Pp, const bf16x8* __restrict__ h1c,
    float* __restrict__ out)
{
    const int tid = threadIdx.x;
    const int wv = tid >> 6, lane = tid & 63;
    const int quad = lane >> 4, l16 = lane & 15;
    const int wt = blockIdx.x * 4 + wv;
    const int b = wt >> 8, rem = wt & 255;
    const int it = rem >> 3, eg = rem & 7;

    const bf16x8* __restrict__ Ab =
        (const bf16x8*)(Pp + (size_t)b * S_ * S_) + (it * 16) * 64 + lane;
    const bf16x8* __restrict__ Bb =
        h1c + ((b * 32 + eg * 4) * 16) * 64 + lane;

    f32x4 acc[4];
#pragma unroll
    for (int i = 0; i < 4; ++i) acc[i] = (f32x4){0.f, 0.f, 0.f, 0.f};

    for (int kc = 0; kc < 16; ++kc) {
        const bf16x8 a8 = Ab[kc * 64];
#pragma unroll
        for (int n = 0; n < 4; ++n) {
            const bf16x8 b8 = Bb[(n * 16 + kc) * 64];
            acc[n] = __builtin_amdgcn_mfma_f32_16x16x32_bf16(a8, b8, acc[n], 0, 0, 0);
        }
    }

    const int i = it * 16 + quad * 4;
#pragma unroll
    for (int n = 0; n < 4; ++n) {
        const int e = (eg * 4 + n) * 16 + l16;
        float* __restrict__ ob = out + ((size_t)b * S_ + i) * E_ + e;
#pragma unroll
        for (int r = 0; r < 4; ++r)
            ob[(size_t)r * E_] = acc[n][r];
    }
}

extern "C" void kernel_launch(void* const* d_in, const int* in_sizes, int n_in,
                              void* d_out, int out_size, void* d_ws, size_t ws_size,
                              hipStream_t stream) {
    const float* h1 = (const float*)d_in[0];
    const float* h2 = (const float*)d_in[1];
    const float* w  = (const float*)d_in[2];
    const float* b1 = (const float*)d_in[3];
    const float* v  = (const float*)d_in[4];
    // d_in[5] = b2: cancels in softmax, unused.
    float* out = (float*)d_out;

    char* ws = (char*)d_ws;
    float* keySt = (float*)ws;                 ws += 2u << 20;  // 2 MB
    float* qryS  = (float*)ws;                 ws += 2u << 20;  // 2 MB
    unsigned short* Pp = (unsigned short*)ws;  ws += 2u << 20;  // 2 MB
    bf16x8* h1c = (bf16x8*)ws;                                  // 2 MB

    prep_gemm<<<dim3(1024), dim3(256), 0, stream>>>(h1, h2, w, b1, keySt, qryS, h1c);
    scores_kernel<<<dim3(S_ / 4, B_), dim3(512), 0, stream>>>(keySt, qryS, v, Pp);
    pv_gemm<<<dim3(256), dim3(256), 0, stream>>>(Pp, h1c, out);
}